// Round 2
// baseline (438.143 us; speedup 1.0000x reference)
//
#include <hip/hip_runtime.h>
#include <hip/hip_bf16.h>

#define LSEQ 2048
#define BB 2
#define DD 128
#define HH 8
#define HD 32

typedef __bf16 bf8_t __attribute__((ext_vector_type(8)));
typedef float f4_t __attribute__((ext_vector_type(4)));

// ---------------- kernel 0a: xp = bf16(x + pe) ----------------
__global__ __launch_bounds__(256) void k_xpb(const float* __restrict__ x,
                                             const float* __restrict__ pe,
                                             __bf16* __restrict__ xpb) {
    int idx = blockIdx.x * 256 + threadIdx.x;     // 0..524287 (4096*128)
    int d = idx & 127;
    int l = (idx >> 7) & (LSEQ - 1);
    float v = x[idx] + pe[l * DD + d];
    xpb[idx] = (__bf16)v;
}

// ---------------- kernel 0b: transpose Wq/Wk -> [c][d] bf16 ----------------
__global__ __launch_bounds__(256) void k_wtrans(const float* __restrict__ Wq,
                                                const float* __restrict__ Wk,
                                                __bf16* __restrict__ WqT,
                                                __bf16* __restrict__ WkT) {
    __shared__ float tile[32][33];
    const float* W = blockIdx.z ? Wk : Wq;
    __bf16* WT = blockIdx.z ? WkT : WqT;
    int d0 = blockIdx.x * 32, c0 = blockIdx.y * 32;
    int tr = threadIdx.x >> 5, tc = threadIdx.x & 31;
    for (int i = 0; i < 4; i++)
        tile[tr + i * 8][tc] = W[(d0 + tr + i * 8) * 256 + c0 + tc];
    __syncthreads();
    for (int i = 0; i < 4; i++)
        WT[(c0 + tr + i * 8) * 128 + d0 + tc] = (__bf16)tile[tc][tr + i * 8];
}

// ---------------- kernel 0c: w[hb][k] = sigmoid(x[b,L-1-k] . Wv[:,h]) ------
__global__ __launch_bounds__(256) void k_wv(const float* __restrict__ x,
                                            const float* __restrict__ Wv,
                                            float* __restrict__ w) {
    __shared__ float xs[32 * 132];
    __shared__ float wv[128 * 8];
    int r0 = blockIdx.x * 32;                       // 32 rows per block
    for (int i = 0; i < 16; i++) {
        int idx = threadIdx.x + i * 256;            // 0..4095
        xs[(idx >> 7) * 132 + (idx & 127)] = x[r0 * 128 + idx];
    }
    for (int i = 0; i < 4; i++) {
        int idx = threadIdx.x + i * 256;            // 0..1023
        wv[idx] = Wv[idx];
    }
    __syncthreads();
    int rl = threadIdx.x >> 3, h = threadIdx.x & 7;
    float acc = 0.f;
    #pragma unroll 8
    for (int d = 0; d < 128; d++) acc += xs[rl * 132 + d] * wv[d * 8 + h];
    float sg = 1.f / (1.f + __expf(-acc));
    int r = r0 + rl;
    int b = r >> 11, l = r & (LSEQ - 1);
    w[(h * BB + b) * LSEQ + (LSEQ - 1 - l)] = sg;
}

// ---------------- kernel 1: Q/K = xp @ W (+bias), MFMA, store bf16 ---------
__global__ __launch_bounds__(256) void k_qk(const __bf16* __restrict__ xpb,
                                            const __bf16* __restrict__ WqT,
                                            const __bf16* __restrict__ WkT,
                                            const float* __restrict__ bq,
                                            const float* __restrict__ bk,
                                            __bf16* __restrict__ Qb,
                                            __bf16* __restrict__ Kb) {
    // grid (256, 8); wave computes a 16x16 output tile, K-dim 128
    int wid = threadIdx.x >> 6, lane = threadIdx.x & 63;
    int row0 = blockIdx.x * 16;
    int col0 = blockIdx.y * 64 + wid * 16;          // 0..511
    bool isK = col0 >= 256;
    int c0 = isK ? col0 - 256 : col0;
    const __bf16* WT = isK ? WkT : WqT;
    const float* bias = isK ? bk : bq;
    __bf16* Out = isK ? Kb : Qb;

    int lm = lane & 15, lq = lane >> 4;
    f4_t acc = {0.f, 0.f, 0.f, 0.f};
    const __bf16* aptr = xpb + (row0 + lm) * 128 + lq * 8;
    const __bf16* bptr = WT + (c0 + lm) * 128 + lq * 8;
    #pragma unroll
    for (int s = 0; s < 4; s++) {
        bf8_t a = *(const bf8_t*)(aptr + s * 32);
        bf8_t bfr = *(const bf8_t*)(bptr + s * 32);
        acc = __builtin_amdgcn_mfma_f32_16x16x32_bf16(a, bfr, acc, 0, 0, 0);
    }
    int c = c0 + lm;
    float bv = bias[c];
    int h = c >> 5, hd = c & 31;
    #pragma unroll
    for (int r = 0; r < 4; r++) {
        int row = row0 + lq * 4 + r;                // = b*2048 + l
        int b_ = row >> 11, l = row & (LSEQ - 1);
        Out[((h * BB + b_) * LSEQ + l) * HD + hd] = (__bf16)(acc[r] + bv);
    }
}

// ---------------- zero S ----------------
__global__ void k_zero(float* __restrict__ S) {
    S[blockIdx.x * 256 + threadIdx.x] = 0.f;
}

// ---------------- kernel 2: fused softmax + diagonal-weighted sums ---------
__global__ __launch_bounds__(256) void k_attn(const __bf16* __restrict__ Qb,
                                              const __bf16* __restrict__ Kb,
                                              const float* __restrict__ w,
                                              float* __restrict__ S) {
    int hb = blockIdx.y;
    int q0 = blockIdx.x * 64;
    int wid = threadIdx.x >> 6, lane = threadIdx.x & 63;
    int lm = lane & 15, lq = lane >> 4;
    int qw0 = q0 + wid * 16;                        // this wave's 16 q-rows

    __shared__ float Sloc[2048];
    __shared__ __bf16 Kt[64 * 32] __attribute__((aligned(16)));
    __shared__ float wt[64];
    __shared__ float rden[64];

    for (int i = threadIdx.x; i < 2048; i += 256) Sloc[i] = 0.f;

    // A-fragment: Q rows, HD=32 = one MFMA K-step
    bf8_t aq = *(const bf8_t*)(Qb + (hb * LSEQ + qw0 + lm) * HD + lq * 8);
    const float scale = 0.17677669529663687f;       // 1/sqrt(32)
    const __bf16* Khb = Kb + hb * LSEQ * HD;

    // ---- sweep A: softmax denominators over all k ----
    float dsum[4] = {0.f, 0.f, 0.f, 0.f};
    for (int kb = 0; kb < 32; kb++) {
        __syncthreads();
        ((uint4*)Kt)[threadIdx.x] =
            ((const uint4*)(Khb + kb * 64 * HD))[threadIdx.x];
        __syncthreads();
        #pragma unroll
        for (int sub = 0; sub < 4; sub++) {
            bf8_t bk_ = *(const bf8_t*)(Kt + (sub * 16 + lm) * HD + lq * 8);
            f4_t z = {0.f, 0.f, 0.f, 0.f};
            f4_t sc = __builtin_amdgcn_mfma_f32_16x16x32_bf16(aq, bk_, z, 0, 0, 0);
            dsum[0] += __expf(sc[0] * scale);
            dsum[1] += __expf(sc[1] * scale);
            dsum[2] += __expf(sc[2] * scale);
            dsum[3] += __expf(sc[3] * scale);
        }
    }
    #pragma unroll
    for (int r = 0; r < 4; r++) {
        float v = dsum[r];
        v += __shfl_xor(v, 1);
        v += __shfl_xor(v, 2);
        v += __shfl_xor(v, 4);
        v += __shfl_xor(v, 8);
        dsum[r] = v;
    }
    if (lm == 0) {
        #pragma unroll
        for (int r = 0; r < 4; r++)
            rden[wid * 16 + lq * 4 + r] = 1.f / dsum[r];
    }
    __syncthreads();
    float rdv[4];
    #pragma unroll
    for (int r = 0; r < 4; r++) rdv[r] = rden[wid * 16 + lq * 4 + r];

    // ---- sweep B: k >= q triangle, scatter into diagonal accumulator ----
    int kb0 = q0 >> 6;
    for (int kb = kb0; kb < 32; kb++) {
        __syncthreads();
        ((uint4*)Kt)[threadIdx.x] =
            ((const uint4*)(Khb + kb * 64 * HD))[threadIdx.x];
        if (threadIdx.x < 64) wt[threadIdx.x] = w[hb * LSEQ + kb * 64 + threadIdx.x];
        __syncthreads();
        #pragma unroll
        for (int sub = 0; sub < 4; sub++) {
            int k0s = kb * 64 + sub * 16;
            if (k0s + 15 < qw0) continue;           // whole subtile below diagonal
            bf8_t bk_ = *(const bf8_t*)(Kt + (sub * 16 + lm) * HD + lq * 8);
            f4_t z = {0.f, 0.f, 0.f, 0.f};
            f4_t sc = __builtin_amdgcn_mfma_f32_16x16x32_bf16(aq, bk_, z, 0, 0, 0);
            float wv = wt[sub * 16 + lm];
            int kcol = k0s + lm;
            #pragma unroll
            for (int r = 0; r < 4; r++) {
                int m = kcol - (qw0 + lq * 4 + r);
                if (m >= 0) {
                    float val = __expf(sc[r] * scale) * wv * rdv[r];
                    __hip_atomic_fetch_add(&Sloc[m], val, __ATOMIC_RELAXED,
                                           __HIP_MEMORY_SCOPE_WORKGROUP);
                }
            }
        }
    }
    __syncthreads();
    int mlen = 2048 - q0;
    for (int i = threadIdx.x; i < mlen; i += 256)
        __hip_atomic_fetch_add(&S[hb * LSEQ + i], Sloc[i], __ATOMIC_RELAXED,
                               __HIP_MEMORY_SCOPE_AGENT);
}

// ---------------- kernel 3: pooling epilogue ----------------
__global__ __launch_bounds__(256) void k_out(const float* __restrict__ S,
                                             float* __restrict__ out) {
    int idx = blockIdx.x * 256 + threadIdx.x;       // (b*2048 + m)*8 + h
    int h = idx & 7;
    int m = (idx >> 3) & (LSEQ - 1);
    int b = idx >> 14;
    const float* Sr = S + (h * BB + b) * LSEQ;
    float s = Sr[m];
    float cnt = 3.f;
    if (m > 0) s += Sr[m - 1]; else cnt = 2.f;
    if (m < LSEQ - 1) s += Sr[m + 1]; else cnt = 2.f;
    out[idx] = s / cnt;
}

extern "C" void kernel_launch(void* const* d_in, const int* in_sizes, int n_in,
                              void* d_out, int out_size, void* d_ws, size_t ws_size,
                              hipStream_t stream) {
    const float* x  = (const float*)d_in[0];
    const float* pe = (const float*)d_in[1];
    const float* Wq = (const float*)d_in[2];
    const float* bq = (const float*)d_in[3];
    const float* Wk = (const float*)d_in[4];
    const float* bk = (const float*)d_in[5];
    const float* Wv = (const float*)d_in[6];
    float* out = (float*)d_out;

    char* ws = (char*)d_ws;
    float*  S    = (float*)(ws);                            // 128 KB
    float*  w    = (float*)(ws + 131072);                   // 128 KB
    __bf16* Qb   = (__bf16*)(ws + 262144);                  // 2 MB
    __bf16* Kb   = (__bf16*)(ws + 262144 + 2097152);        // 2 MB
    __bf16* xpb  = (__bf16*)(ws + 262144 + 4194304);        // 1 MB
    __bf16* WqT  = (__bf16*)(ws + 262144 + 4194304 + 1048576);   // 64 KB
    __bf16* WkT  = (__bf16*)(ws + 262144 + 4194304 + 1048576 + 65536);

    k_xpb<<<2048, 256, 0, stream>>>(x, pe, xpb);
    k_wtrans<<<dim3(4, 8, 2), 256, 0, stream>>>(Wq, Wk, WqT, WkT);
    k_wv<<<128, 256, 0, stream>>>(x, Wv, w);
    k_zero<<<128, 256, 0, stream>>>(S);
    k_qk<<<dim3(256, 8), 256, 0, stream>>>(xpb, WqT, WkT, bq, bk, Qb, Kb);
    k_attn<<<dim3(32, 16), 256, 0, stream>>>(Qb, Kb, w, S);
    k_out<<<128, 256, 0, stream>>>(S, out);
}